// Round 13
// baseline (324.425 us; speedup 1.0000x reference)
//
#include <hip/hip_runtime.h>
#include <hip/hip_bf16.h>

#define N_NODES 50000
#define N_EDGES 800000
#define ZROW    N_NODES
#define PADCAP  (N_EDGES + 8 * N_NODES + 64)
#define NCLS    8
#define CLSW    6250   /* nodes per dst-class: 8*6250 = 50000 */
#define FUSED_LDS_BYTES ((16384 + 8192 + 64 * 520) * 2)

typedef short  short8  __attribute__((ext_vector_type(8)));
typedef float  floatx4 __attribute__((ext_vector_type(4)));

__device__ __forceinline__ short f2bf(float f) {
    union { __hip_bfloat16 h; short s; } u;
    u.h = __float2bfloat16(f);
    return u.s;
}
__device__ __forceinline__ unsigned packbf(float lo, float hi) {
    return ((unsigned)(unsigned short)f2bf(hi) << 16) | (unsigned short)f2bf(lo);
}

// dword (2 packed bf16) dot-accumulate via v_dot2_f32_bf16 inline asm
// (builtin ABI takes short2; (__bf16) value-casts corrupt selectors — r6).
__device__ __forceinline__ void acc2(unsigned v, float& ax, float& ay,
                                     unsigned selLo, unsigned selHi) {
    asm("v_dot2_f32_bf16 %0, %1, %2, %0" : "+v"(ax) : "v"(v), "v"(selLo));
    asm("v_dot2_f32_bf16 %0, %1, %2, %0" : "+v"(ay) : "v"(v), "v"(selHi));
}

__device__ __forceinline__ void gld_lds16(const short* g, short* l) {
    __builtin_amdgcn_global_load_lds(
        (const __attribute__((address_space(1))) int*)g,
        (__attribute__((address_space(3))) int*)l, 16, 0, 0);
}

// ---------------------------------------------------------------- init
__global__ void k_init(int* __restrict__ deg, int* __restrict__ col,
                       int* __restrict__ zrowA, int* __restrict__ zrowY) {
    int i = blockIdx.x * 256 + threadIdx.x;
    if (i < PADCAP) col[i] = ZROW;
    if (i < N_NODES) deg[i] = 0;
    if (i < 128) zrowA[i] = 0;   // Abf zero row: 256 bf16 = 128 ints
    if (i < 64)  zrowY[i] = 0;   // y1bf zero row: 128 bf16 = 64 ints
}

// ---------------------------------------------------------------- CSR build
__global__ void k_deg(const int* __restrict__ dst, int* __restrict__ deg) {
    int e = blockIdx.x * 256 + threadIdx.x;
    if (e < N_EDGES) atomicAdd(&deg[dst[e]], 1);
}

// scans use PADDED degrees (deg+7)&~7: every edge list multiple of 8,
// tail slots stay ZROW -> gather adds exact zeros, no masks needed.
__global__ __launch_bounds__(1024) void k_scan1(const int* __restrict__ deg,
                                                int* __restrict__ bsum,
                                                float* __restrict__ dinv) {
    __shared__ int ws[16];
    int b = blockIdx.x, t = threadIdx.x, i = b * 1024 + t;
    int lane = t & 63, wid = t >> 6;
    int v = (i < N_NODES) ? deg[i] : 0;
    if (i < N_NODES) dinv[i] = 1.0f / fmaxf((float)v, 1.0f);
    int x = (v + 7) & ~7;
    #pragma unroll
    for (int off = 1; off < 64; off <<= 1) x += __shfl_xor(x, off, 64);
    if (lane == 0) ws[wid] = x;
    __syncthreads();
    if (t == 0) {
        int s = 0;
        #pragma unroll
        for (int k = 0; k < 16; ++k) s += ws[k];
        bsum[b] = s;
    }
}

__global__ void k_scan2(const int* __restrict__ bsum, int* __restrict__ boff) {
    int lane = threadIdx.x;
    int v = (lane < 49) ? bsum[lane] : 0;
    int x = v;
    #pragma unroll
    for (int off = 1; off < 64; off <<= 1) {
        int y = __shfl_up(x, off, 64);
        if (lane >= off) x += y;
    }
    if (lane < 49) boff[lane] = x - v;
}

__global__ __launch_bounds__(1024) void k_scan3(const int* __restrict__ deg,
                                                const int* __restrict__ boff,
                                                int* __restrict__ rowptr,
                                                int* __restrict__ cursor) {
    __shared__ int ws[16];
    int b = blockIdx.x, t = threadIdx.x, i = b * 1024 + t;
    int lane = t & 63, wid = t >> 6;
    int v = (i < N_NODES) ? ((deg[i] + 7) & ~7) : 0;
    int x = v;
    #pragma unroll
    for (int off = 1; off < 64; off <<= 1) {
        int y = __shfl_up(x, off, 64);
        if (lane >= off) x += y;
    }
    if (lane == 63) ws[wid] = x;
    __syncthreads();
    if (wid == 0) {
        int s = (lane < 16) ? ws[lane] : 0;
        #pragma unroll
        for (int off = 1; off < 16; off <<= 1) {
            int y = __shfl_up(s, off, 64);
            if (lane >= off) s += y;
        }
        if (lane < 16) ws[lane] = s;
    }
    __syncthreads();
    int waveOff = (wid == 0) ? 0 : ws[wid - 1];
    int incl = x + waveOff + boff[b];
    if (i < N_NODES) { rowptr[i + 1] = incl; cursor[i] = incl - v; }
    if (b == 0 && t == 0) rowptr[0] = 0;
}

// XCD-classed fill (single-owner col slices -> no 16x write amplification)
__global__ __launch_bounds__(256) void k_fill(
    const int* __restrict__ src, const int* __restrict__ dst,
    int* __restrict__ cursor, int* __restrict__ col) {
    int b = blockIdx.x;
    int e = (b >> 3) * 256 + threadIdx.x;
    int lo = (b & 7) * CLSW;
    if (e < N_EDGES) {
        int d = dst[e];
        if ((unsigned)(d - lo) < CLSW) {
            int p = atomicAdd(&cursor[d], 1);
            col[p] = src[e];
        }
    }
}

// ------------------------------------------- fused bf16 conversions
__global__ void k_cvt(const float* __restrict__ feat,
                      const float* __restrict__ W1s, const float* __restrict__ W1n,
                      const float* __restrict__ W2s, const float* __restrict__ W2n,
                      const float* __restrict__ Wp1, const float* __restrict__ Wp2,
                      short* __restrict__ Abf, short* __restrict__ W1T,
                      short* __restrict__ W2T, float* __restrict__ Wp2T,
                      unsigned* __restrict__ W1pk) {
    int bb = blockIdx.x, t = threadIdx.x;
    if (bb < 6250) {
        int idx = bb * 256 + t;
        if (idx >= N_NODES * 32) return;
        int n = idx >> 5, c = (idx & 31) * 4;
        float4 v = *(const float4*)(feat + (size_t)n * 128 + c);
        *(short4*)(Abf + (size_t)n * 256 + c) =
            make_short4(f2bf(v.x), f2bf(v.y), f2bf(v.z), f2bf(v.w));
    } else {
        int idx = (bb - 6250) * 256 + t;
        if (idx < 512 * 256) {
            int n = idx >> 8, k = idx & 255;
            float v = (k < 128) ? W1s[(size_t)k * 512 + n]
                                : W1n[(size_t)(k - 128) * 512 + n];
            W1T[idx] = f2bf(v);
        } else if (idx < 2 * 512 * 256) {
            int j = idx - 512 * 256;
            int n = j >> 9, k = j & 511;
            float v = (n < 128) ? W2s[(size_t)k * 128 + n]
                                : W2n[(size_t)k * 128 + (n - 128)];
            W2T[j] = f2bf(v);
        } else {
            int r = idx - 2 * 512 * 256;
            if (r < 256) {
                Wp2T[r] = Wp2[(r & 31) * 8 + (r >> 5)];
            } else if (r < 256 + 2048) {
                int q = r - 256;
                int jj = q & 31, kp = (q >> 5) & 31, hh = q >> 10;
                int k0 = hh * 64 + 2 * kp;
                W1pk[q] = packbf(Wp1[(size_t)k0 * 32 + jj],
                                 Wp1[(size_t)(k0 + 1) * 32 + jj]);
            }
        }
    }
}

// -------- wave-per-node gather core: scalar-base (readlane) row loads.
template<int STRIDE>
__device__ __forceinline__ float2 wave_gather(
    const unsigned* __restrict__ U, const int* __restrict__ col,
    int s, int e, int lane) {
    float ax = 0.f, ay = 0.f;
    unsigned selLo = 0x00003F80u;   // bf16 pair (1.0, 0.0)
    unsigned selHi = 0x3F800000u;   // bf16 pair (0.0, 1.0)
    for (int base = s; base < e; base += 64) {
        int cnt = e - base; if (cnt > 64) cnt = 64;   // multiple of 8
        int myc = col[base + lane];                    // padded: always valid
        int j = 0;
        for (; j + 16 <= cnt; j += 16) {
            unsigned v[16];
            #pragma unroll
            for (int u = 0; u < 16; ++u) {
                int c = __builtin_amdgcn_readlane(myc, j + u);
                v[u] = U[(size_t)c * STRIDE + lane];
            }
            #pragma unroll
            for (int u = 0; u < 16; ++u) acc2(v[u], ax, ay, selLo, selHi);
        }
        for (; j < cnt; j += 8) {
            unsigned v[8];
            #pragma unroll
            for (int u = 0; u < 8; ++u) {
                int c = __builtin_amdgcn_readlane(myc, j + u);
                v[u] = U[(size_t)c * STRIDE + lane];
            }
            #pragma unroll
            for (int u = 0; u < 8; ++u) acc2(v[u], ax, ay, selLo, selHi);
        }
    }
    return make_float2(ax, ay);
}

// ---------------------------------------------- aggregation 1 (bf16 gather)
__global__ __launch_bounds__(256) void k_agg(
    const unsigned* __restrict__ Au, const int* __restrict__ rowptr,
    const int* __restrict__ col, const float* __restrict__ dinv,
    unsigned* __restrict__ Aw) {
    int t = threadIdx.x, lane = t & 63, w = t >> 6;
    int n = blockIdx.x * 4 + w;
    int s = rowptr[n], e = rowptr[n + 1];
    float2 a = wave_gather<128>(Au, col, s, e, lane);
    float dv = dinv[n];
    Aw[(size_t)n * 128 + 64 + lane] = packbf(a.x * dv, a.y * dv);
}

// --------------------- aggregation 2 + bias/relu + MLP + softmax (fused)
__global__ __launch_bounds__(256) void k_aggmlp(
    const unsigned* __restrict__ Yu, const int* __restrict__ rowptr,
    const int* __restrict__ col, const float* __restrict__ dinv,
    const float* __restrict__ z, const float* __restrict__ b2,
    const unsigned* __restrict__ W1pk, const float* __restrict__ bp1,
    const float* __restrict__ Wp2T, const float* __restrict__ bp2,
    float* __restrict__ out) {
    __shared__ __align__(16) unsigned h2p[4][64];
    __shared__ __align__(16) float xsh[4][32];
    int t = threadIdx.x, lane = t & 63, w = t >> 6;
    int n = blockIdx.x * 4 + w;
    int s = rowptr[n], e = rowptr[n + 1];
    float2 a = wave_gather<64>(Yu, col, s, e, lane);
    float dv = dinv[n];
    float2 zv = *(const float2*)(z + (size_t)n * 128 + 2 * lane);
    float2 bb = *(const float2*)(b2 + 2 * lane);
    float h2x = fmaxf(zv.x + a.x * dv + bb.x, 0.f);
    float h2y = fmaxf(zv.y + a.y * dv + bb.y, 0.f);
    h2p[w][lane] = packbf(h2x, h2y);   // pair (k=2*lane, 2*lane+1)
    // intra-wave consumers only: lockstep, no barrier

    // phase 1: x = relu(h2 @ Wp1 + bp1) in packed-bf16 dot2 form.
    int j = lane & 31, half = lane >> 5;
    const unsigned* wp = W1pk + (half * 32) * 32 + j;
    float p = 0.f;
    #pragma unroll
    for (int kp = 0; kp < 32; ++kp) {
        unsigned hv = h2p[w][half * 32 + kp];
        unsigned wv = wp[kp * 32];
        asm("v_dot2_f32_bf16 %0, %1, %2, %0" : "+v"(p) : "v"(hv), "v"(wv));
    }
    p += __shfl_xor(p, 32, 64);
    if (half == 0) xsh[w][j] = fmaxf(p + bp1[j], 0.f);

    // phase 2: logits + softmax, all 64 lanes (j8 x kg)
    int j8 = lane >> 3, kg = lane & 7;
    float4 xv = *(const float4*)(&xsh[w][kg * 4]);
    float4 wv2 = *(const float4*)(Wp2T + j8 * 32 + kg * 4);
    float pp = xv.x * wv2.x + xv.y * wv2.y + xv.z * wv2.z + xv.w * wv2.w;
    pp += __shfl_xor(pp, 1, 64);
    pp += __shfl_xor(pp, 2, 64);
    pp += __shfl_xor(pp, 4, 64);
    float lg = pp + bp2[j8];
    float mx = lg;
    mx = fmaxf(mx, __shfl_xor(mx, 8, 64));
    mx = fmaxf(mx, __shfl_xor(mx, 16, 64));
    mx = fmaxf(mx, __shfl_xor(mx, 32, 64));
    float ev = expf(lg - mx);
    float sm = ev;
    sm += __shfl_xor(sm, 8, 64);
    sm += __shfl_xor(sm, 16, 64);
    sm += __shfl_xor(sm, 32, 64);
    if (kg == 0) out[(size_t)n * 8 + j8] = ev / sm;
}

// ------------------------------------- FUSED GEMM1+GEMM2 (kills h1bf HBM
// round-trip: was 102 MB of the two GEMMs' 205 MB traffic; both ran at 11%
// MfmaUtil, 2.7x memory roofline — latency/line-rate bound, r10/r12 PMC).
// Block = 64-row node slab. Phase 1: A slab (8 swizzled k-tiles, staged
// once) x W1T tiles -> h1[64][520] bf16 in LDS (pad 8 shorts: row stride
// = 4 banks mod 32 -> 2-way conflict = free). Phase 2: h1 (row-major
// ds_read; staging XOR provably cancels so plain q8 col-group is the MFMA
// layout) x W2T tiles -> z (fp32) + y1bf. Weights are L2-resident.
__global__ __launch_bounds__(256) void k_gemm12(
    const short* __restrict__ A, const short* __restrict__ W1T,
    const float* __restrict__ b1, const short* __restrict__ W2T,
    float* __restrict__ z, short* __restrict__ y1bf) {
    extern __shared__ short smem[];
    short* A_lds  = smem;            // 8 k-tiles x [64][32]
    short* wstage = smem + 16384;    // 2 bufs x [128][32]
    short* h1     = smem + 24576;    // [64][520]
    short* sOut   = wstage;          // y epilogue reuse (exactly 8192 shorts)

    const int t = threadIdx.x;
    const int lane = t & 63;
    const int w = t >> 6;
    const int mBase = blockIdx.x * 64;

    const int rL = lane >> 2;
    const int cg = (((lane & 3) ^ ((lane >> 3) & 3))) * 8;
    const int fr = lane & 15;
    const int csel = (((lane >> 4) ^ ((lane >> 1) & 3))) * 8;
    const int q8 = (lane >> 4) * 8;
    const int mOff = (w & 1) * 32;
    const int nOff = (w >> 1) * 64;
    const int cn = lane & 15;
    const int cm = (lane >> 4) * 4;

    // stage A slab (64 rows x 256 k) once: wave w covers rows w*16..w*16+15
    {
        const long ar = (long)min(mBase + w * 16 + rL, N_NODES - 1) * 256 + cg;
        #pragma unroll
        for (int kt = 0; kt < 8; ++kt)
            gld_lds16(A + ar + kt * 32, A_lds + kt * 2048 + (w * 16) * 32);
    }

    floatx4 zero4 = {0.f, 0.f, 0.f, 0.f};
    floatx4 acc[2][4];

    // ---------------- phase 1: h1 = relu(A @ W1 + b1), 4 x 128-col chunks
    {
        const long r0base = (long)(w * 32 + rL) * 256 + cg;
        auto stage1 = [&](int b, int step) {
            int nc = step >> 3, kt = step & 7;
            const long r0 = r0base + (long)nc * (128 * 256) + kt * 32;
            short* d = wstage + b * 4096 + (w * 32) * 32;
            gld_lds16(W1T + r0,            d);
            gld_lds16(W1T + r0 + 16 * 256, d + 16 * 32);
        };
        stage1(0, 0);
        int cur = 0;
        for (int nc = 0; nc < 4; ++nc) {
            #pragma unroll
            for (int mi = 0; mi < 2; ++mi)
                #pragma unroll
                for (int ni = 0; ni < 4; ++ni) acc[mi][ni] = zero4;
            for (int kt = 0; kt < 8; ++kt) {
                int step = nc * 8 + kt;
                __syncthreads();                       // tile landed / buf free
                if (step + 1 < 32) stage1(cur ^ 1, step + 1);
                const short* sB = wstage + cur * 4096;
                short8 af[2], bf[4];
                #pragma unroll
                for (int i = 0; i < 2; ++i)
                    af[i] = *(const short8*)(A_lds + kt * 2048 +
                                             (mOff + i * 16 + fr) * 32 + csel);
                #pragma unroll
                for (int i = 0; i < 4; ++i)
                    bf[i] = *(const short8*)(sB + (nOff + i * 16 + fr) * 32 + csel);
                #pragma unroll
                for (int mi = 0; mi < 2; ++mi)
                    #pragma unroll
                    for (int ni = 0; ni < 4; ++ni)
                        acc[mi][ni] = __builtin_amdgcn_mfma_f32_16x16x32_bf16(
                            af[mi], bf[ni], acc[mi][ni], 0, 0, 0);
                cur ^= 1;
            }
            // chunk epilogue: bias+relu -> h1 (row-major, 2B writes)
            #pragma unroll
            for (int ni = 0; ni < 4; ++ni) {
                int colc = nc * 128 + nOff + ni * 16 + cn;
                float bv = b1[colc];
                #pragma unroll
                for (int mi = 0; mi < 2; ++mi)
                    #pragma unroll
                    for (int r = 0; r < 4; ++r)
                        h1[(mOff + mi * 16 + cm + r) * 520 + colc] =
                            f2bf(fmaxf(acc[mi][ni][r] + bv, 0.f));
            }
        }
    }
    __syncthreads();   // h1 complete for all waves; wstage free

    // ---------------- phase 2: [z | y1] = h1 @ W2, 2 x 128-col chunks
    {
        const long r0base = (long)(w * 32 + rL) * 512 + cg;
        auto stage2 = [&](int b, int step) {
            int nc = step >> 4, kt = step & 15;
            const long r0 = r0base + (long)nc * (128 * 512) + kt * 32;
            short* d = wstage + b * 4096 + (w * 32) * 32;
            gld_lds16(W2T + r0,            d);
            gld_lds16(W2T + r0 + 16 * 512, d + 16 * 32);
        };
        stage2(0, 0);
        int cur = 0;
        for (int nc2 = 0; nc2 < 2; ++nc2) {
            #pragma unroll
            for (int mi = 0; mi < 2; ++mi)
                #pragma unroll
                for (int ni = 0; ni < 4; ++ni) acc[mi][ni] = zero4;
            for (int kt = 0; kt < 16; ++kt) {
                int step = nc2 * 16 + kt;
                __syncthreads();
                if (step + 1 < 32) stage2(cur ^ 1, step + 1);
                const short* sB = wstage + cur * 4096;
                short8 af[2], bf[4];
                #pragma unroll
                for (int i = 0; i < 2; ++i)
                    af[i] = *(const short8*)(h1 + (mOff + i * 16 + fr) * 520 +
                                             kt * 32 + q8);
                #pragma unroll
                for (int i = 0; i < 4; ++i)
                    bf[i] = *(const short8*)(sB + (nOff + i * 16 + fr) * 32 + csel);
                #pragma unroll
                for (int mi = 0; mi < 2; ++mi)
                    #pragma unroll
                    for (int ni = 0; ni < 4; ++ni)
                        acc[mi][ni] = __builtin_amdgcn_mfma_f32_16x16x32_bf16(
                            af[mi], bf[ni], acc[mi][ni], 0, 0, 0);
                cur ^= 1;
            }
            if (nc2 == 0) {
                // z (fp32): direct stores, 16-lane x 4B = 64B bursts
                #pragma unroll
                for (int ni = 0; ni < 4; ++ni) {
                    int n = nOff + ni * 16 + cn;
                    #pragma unroll
                    for (int mi = 0; mi < 2; ++mi)
                        #pragma unroll
                        for (int r = 0; r < 4; ++r) {
                            int m = mBase + mOff + mi * 16 + cm + r;
                            if (m < N_NODES) z[(size_t)m * 128 + n] = acc[mi][ni][r];
                        }
                }
            } else {
                // y1bf: stage in sOut (reuses wstage), full-line stores
                __syncthreads();
                #pragma unroll
                for (int ni = 0; ni < 4; ++ni)
                    #pragma unroll
                    for (int mi = 0; mi < 2; ++mi)
                        #pragma unroll
                        for (int r = 0; r < 4; ++r)
                            sOut[(mOff + mi * 16 + cm + r) * 128 +
                                 nOff + ni * 16 + cn] = f2bf(acc[mi][ni][r]);
                __syncthreads();
                int r0 = t >> 2, c0 = (t & 3) * 32;
                int m = mBase + r0;
                if (m < N_NODES) {
                    const short* sp = sOut + r0 * 128 + c0;
                    short* gp = y1bf + (size_t)m * 128 + c0;
                    #pragma unroll
                    for (int qq = 0; qq < 4; ++qq)
                        *(short8*)(gp + qq * 8) = *(const short8*)(sp + qq * 8);
                }
            }
        }
    }
}

// ---------------------------------------------------------------- launch
extern "C" void kernel_launch(void* const* d_in, const int* in_sizes, int n_in,
                              void* d_out, int out_size, void* d_ws, size_t ws_size,
                              hipStream_t stream) {
    const float* feat   = (const float*)d_in[0];
    const int*   src    = (const int*)d_in[1];
    const int*   dst    = (const int*)d_in[2];
    const float* W1s    = (const float*)d_in[3];
    const float* W1n    = (const float*)d_in[4];
    const float* b1     = (const float*)d_in[5];
    const float* W2s    = (const float*)d_in[6];
    const float* W2n    = (const float*)d_in[7];
    const float* b2     = (const float*)d_in[8];
    const float* Wp1    = (const float*)d_in[9];
    const float* bp1    = (const float*)d_in[10];
    const float* Wp2    = (const float*)d_in[11];
    const float* bp2    = (const float*)d_in[12];
    float* out = (float*)d_out;

    char* w = (char*)d_ws;
    size_t off = 0;
    auto alloc = [&](size_t bytes) { char* p = w + off; off += (bytes + 255) & ~(size_t)255; return p; };
    int*   deg    = (int*)alloc(N_NODES * 4);
    int*   rowptr = (int*)alloc((N_NODES + 1) * 4);
    int*   cursor = (int*)alloc(N_NODES * 4);
    int*   col    = (int*)alloc((size_t)PADCAP * 4);
    float* dinv   = (float*)alloc(N_NODES * 4);
    int*   bsum   = (int*)alloc(64 * 4);
    int*   boff   = (int*)alloc(64 * 4);
    short* Abf    = (short*)alloc((size_t)(N_NODES + 1) * 256 * 2); // +zero row
    short* W1T    = (short*)alloc((size_t)512 * 256 * 2);
    short* W2T    = (short*)alloc((size_t)256 * 512 * 2);
    float* z      = (float*)alloc((size_t)N_NODES * 128 * 4);
    short* y1bf   = (short*)alloc((size_t)(N_NODES + 1) * 128 * 2); // +zero row
    float* Wp2T   = (float*)alloc((size_t)8 * 32 * 4);
    unsigned* W1pk = (unsigned*)alloc((size_t)2048 * 4);

    static bool attrSet = false;
    if (!attrSet) {
        hipFuncSetAttribute((const void*)k_gemm12,
                            hipFuncAttributeMaxDynamicSharedMemorySize,
                            FUSED_LDS_BYTES);
        attrSet = true;
    }

    k_init<<<(PADCAP + 255) / 256, 256, 0, stream>>>(
        deg, col, (int*)(Abf + (size_t)N_NODES * 256),
        (int*)(y1bf + (size_t)N_NODES * 128));
    k_deg<<<N_EDGES / 256, 256, 0, stream>>>(dst, deg);
    k_scan1<<<49, 1024, 0, stream>>>(deg, bsum, dinv);
    k_scan2<<<1, 64, 0, stream>>>(bsum, boff);
    k_scan3<<<49, 1024, 0, stream>>>(deg, boff, rowptr, cursor);
    k_fill<<<NCLS * (N_EDGES / 256), 256, 0, stream>>>(src, dst, cursor, col);
    k_cvt<<<7283, 256, 0, stream>>>(feat, W1s, W1n, W2s, W2n, Wp1, Wp2,
                                    Abf, W1T, W2T, Wp2T, W1pk);
    k_agg<<<N_NODES / 4, 256, 0, stream>>>((const unsigned*)Abf, rowptr, col, dinv, (unsigned*)Abf);
    k_gemm12<<<(N_NODES + 63) / 64, 256, FUSED_LDS_BYTES, stream>>>(
        Abf, W1T, b1, W2T, z, y1bf);
    k_aggmlp<<<N_NODES / 4, 256, 0, stream>>>((const unsigned*)y1bf, rowptr, col, dinv, z, b2,
                                              W1pk, bp1, Wp2T, bp2, out);
}

// Round 14
// 311.469 us; speedup vs baseline: 1.0416x; 1.0416x over previous
//
#include <hip/hip_runtime.h>
#include <hip/hip_bf16.h>

#define N_NODES 50000
#define N_EDGES 800000
#define ZROW    N_NODES
#define PADCAP  (N_EDGES + 8 * N_NODES + 64)
#define NCLS    8
#define CLSW    6250   /* nodes per dst-class: 8*6250 = 50000 */

typedef short  short8  __attribute__((ext_vector_type(8)));
typedef float  floatx4 __attribute__((ext_vector_type(4)));

__device__ __forceinline__ short f2bf(float f) {
    union { __hip_bfloat16 h; short s; } u;
    u.h = __float2bfloat16(f);
    return u.s;
}
__device__ __forceinline__ unsigned packbf(float lo, float hi) {
    return ((unsigned)(unsigned short)f2bf(hi) << 16) | (unsigned short)f2bf(lo);
}

// dword (2 packed bf16) dot-accumulate via v_dot2_f32_bf16 inline asm
// (builtin ABI takes short2; (__bf16) value-casts corrupt selectors — r6).
__device__ __forceinline__ void acc2(unsigned v, float& ax, float& ay,
                                     unsigned selLo, unsigned selHi) {
    asm("v_dot2_f32_bf16 %0, %1, %2, %0" : "+v"(ax) : "v"(v), "v"(selLo));
    asm("v_dot2_f32_bf16 %0, %1, %2, %0" : "+v"(ay) : "v"(v), "v"(selHi));
}

__device__ __forceinline__ void gld_lds16(const short* g, short* l) {
    __builtin_amdgcn_global_load_lds(
        (const __attribute__((address_space(1))) int*)g,
        (__attribute__((address_space(3))) int*)l, 16, 0, 0);
}

// ---------------------------------------------------------------- init
__global__ void k_init(int* __restrict__ deg, int* __restrict__ col,
                       int* __restrict__ zrowA, int* __restrict__ zrowY) {
    int i = blockIdx.x * 256 + threadIdx.x;
    if (i < PADCAP) col[i] = ZROW;
    if (i < N_NODES) deg[i] = 0;
    if (i < 128) zrowA[i] = 0;   // Abf zero row: 256 bf16 = 128 ints
    if (i < 64)  zrowY[i] = 0;   // y1bf zero row: 128 bf16 = 64 ints
}

// ---------------------------------------------------------------- CSR build
__global__ void k_deg(const int* __restrict__ dst, int* __restrict__ deg) {
    int e = blockIdx.x * 256 + threadIdx.x;
    if (e < N_EDGES) atomicAdd(&deg[dst[e]], 1);
}

// scans use PADDED degrees (deg+7)&~7: every edge list multiple of 8,
// tail slots stay ZROW -> gather adds exact zeros, no masks needed.
__global__ __launch_bounds__(1024) void k_scan1(const int* __restrict__ deg,
                                                int* __restrict__ bsum,
                                                float* __restrict__ dinv) {
    __shared__ int ws[16];
    int b = blockIdx.x, t = threadIdx.x, i = b * 1024 + t;
    int lane = t & 63, wid = t >> 6;
    int v = (i < N_NODES) ? deg[i] : 0;
    if (i < N_NODES) dinv[i] = 1.0f / fmaxf((float)v, 1.0f);
    int x = (v + 7) & ~7;
    #pragma unroll
    for (int off = 1; off < 64; off <<= 1) x += __shfl_xor(x, off, 64);
    if (lane == 0) ws[wid] = x;
    __syncthreads();
    if (t == 0) {
        int s = 0;
        #pragma unroll
        for (int k = 0; k < 16; ++k) s += ws[k];
        bsum[b] = s;
    }
}

__global__ void k_scan2(const int* __restrict__ bsum, int* __restrict__ boff) {
    int lane = threadIdx.x;
    int v = (lane < 49) ? bsum[lane] : 0;
    int x = v;
    #pragma unroll
    for (int off = 1; off < 64; off <<= 1) {
        int y = __shfl_up(x, off, 64);
        if (lane >= off) x += y;
    }
    if (lane < 49) boff[lane] = x - v;
}

__global__ __launch_bounds__(1024) void k_scan3(const int* __restrict__ deg,
                                                const int* __restrict__ boff,
                                                int* __restrict__ rowptr,
                                                int* __restrict__ cursor) {
    __shared__ int ws[16];
    int b = blockIdx.x, t = threadIdx.x, i = b * 1024 + t;
    int lane = t & 63, wid = t >> 6;
    int v = (i < N_NODES) ? ((deg[i] + 7) & ~7) : 0;
    int x = v;
    #pragma unroll
    for (int off = 1; off < 64; off <<= 1) {
        int y = __shfl_up(x, off, 64);
        if (lane >= off) x += y;
    }
    if (lane == 63) ws[wid] = x;
    __syncthreads();
    if (wid == 0) {
        int s = (lane < 16) ? ws[lane] : 0;
        #pragma unroll
        for (int off = 1; off < 16; off <<= 1) {
            int y = __shfl_up(s, off, 64);
            if (lane >= off) s += y;
        }
        if (lane < 16) ws[lane] = s;
    }
    __syncthreads();
    int waveOff = (wid == 0) ? 0 : ws[wid - 1];
    int incl = x + waveOff + boff[b];
    if (i < N_NODES) { rowptr[i + 1] = incl; cursor[i] = incl - v; }
    if (b == 0 && t == 0) rowptr[0] = 0;
}

// XCD-classed fill (single-owner col slices -> no 16x write amplification)
__global__ __launch_bounds__(256) void k_fill(
    const int* __restrict__ src, const int* __restrict__ dst,
    int* __restrict__ cursor, int* __restrict__ col) {
    int b = blockIdx.x;
    int e = (b >> 3) * 256 + threadIdx.x;
    int lo = (b & 7) * CLSW;
    if (e < N_EDGES) {
        int d = dst[e];
        if ((unsigned)(d - lo) < CLSW) {
            int p = atomicAdd(&cursor[d], 1);
            col[p] = src[e];
        }
    }
}

// ------------------------------------------- fused bf16 conversions
// Builds: Abf (feat bf16), W1T/W2T (bf16 GEMM B), Wp2T (fp32 transposed),
// W1pk (Wp1 packed bf16 pairs for dot2 phase-1).
__global__ void k_cvt(const float* __restrict__ feat,
                      const float* __restrict__ W1s, const float* __restrict__ W1n,
                      const float* __restrict__ W2s, const float* __restrict__ W2n,
                      const float* __restrict__ Wp1, const float* __restrict__ Wp2,
                      short* __restrict__ Abf, short* __restrict__ W1T,
                      short* __restrict__ W2T, float* __restrict__ Wp2T,
                      unsigned* __restrict__ W1pk) {
    int bb = blockIdx.x, t = threadIdx.x;
    if (bb < 6250) {
        int idx = bb * 256 + t;
        if (idx >= N_NODES * 32) return;
        int n = idx >> 5, c = (idx & 31) * 4;
        float4 v = *(const float4*)(feat + (size_t)n * 128 + c);
        *(short4*)(Abf + (size_t)n * 256 + c) =
            make_short4(f2bf(v.x), f2bf(v.y), f2bf(v.z), f2bf(v.w));
    } else {
        int idx = (bb - 6250) * 256 + t;
        if (idx < 512 * 256) {
            int n = idx >> 8, k = idx & 255;
            float v = (k < 128) ? W1s[(size_t)k * 512 + n]
                                : W1n[(size_t)(k - 128) * 512 + n];
            W1T[idx] = f2bf(v);
        } else if (idx < 2 * 512 * 256) {
            int j = idx - 512 * 256;
            int n = j >> 9, k = j & 511;
            float v = (n < 128) ? W2s[(size_t)k * 128 + n]
                                : W2n[(size_t)k * 128 + (n - 128)];
            W2T[j] = f2bf(v);
        } else {
            int r = idx - 2 * 512 * 256;
            if (r < 256) {
                Wp2T[r] = Wp2[(r & 31) * 8 + (r >> 5)];
            } else if (r < 256 + 2048) {
                int q = r - 256;
                int jj = q & 31, kp = (q >> 5) & 31, hh = q >> 10;
                int k0 = hh * 64 + 2 * kp;
                W1pk[q] = packbf(Wp1[(size_t)k0 * 32 + jj],
                                 Wp1[(size_t)(k0 + 1) * 32 + jj]);
            }
        }
    }
}

// -------- wave-per-node gather core: scalar-base (readlane) row loads.
// Padded CSR: (e-s) multiple of 8, col[] always valid -> no masks/branches.
template<int STRIDE>
__device__ __forceinline__ float2 wave_gather(
    const unsigned* __restrict__ U, const int* __restrict__ col,
    int s, int e, int lane) {
    float ax = 0.f, ay = 0.f;
    unsigned selLo = 0x00003F80u;   // bf16 pair (1.0, 0.0)
    unsigned selHi = 0x3F800000u;   // bf16 pair (0.0, 1.0)
    for (int base = s; base < e; base += 64) {
        int cnt = e - base; if (cnt > 64) cnt = 64;   // multiple of 8
        int myc = col[base + lane];                    // padded: always valid
        int j = 0;
        for (; j + 16 <= cnt; j += 16) {
            unsigned v[16];
            #pragma unroll
            for (int u = 0; u < 16; ++u) {
                int c = __builtin_amdgcn_readlane(myc, j + u);
                v[u] = U[(size_t)c * STRIDE + lane];
            }
            #pragma unroll
            for (int u = 0; u < 16; ++u) acc2(v[u], ax, ay, selLo, selHi);
        }
        for (; j < cnt; j += 8) {
            unsigned v[8];
            #pragma unroll
            for (int u = 0; u < 8; ++u) {
                int c = __builtin_amdgcn_readlane(myc, j + u);
                v[u] = U[(size_t)c * STRIDE + lane];
            }
            #pragma unroll
            for (int u = 0; u < 8; ++u) acc2(v[u], ax, ay, selLo, selHi);
        }
    }
    return make_float2(ax, ay);
}

// ---------------------------------------------- aggregation 1 (bf16 gather)
__global__ __launch_bounds__(256) void k_agg(
    const unsigned* __restrict__ Au, const int* __restrict__ rowptr,
    const int* __restrict__ col, const float* __restrict__ dinv,
    unsigned* __restrict__ Aw) {
    int t = threadIdx.x, lane = t & 63, w = t >> 6;
    int n = blockIdx.x * 4 + w;
    int s = rowptr[n], e = rowptr[n + 1];
    float2 a = wave_gather<128>(Au, col, s, e, lane);
    float dv = dinv[n];
    Aw[(size_t)n * 128 + 64 + lane] = packbf(a.x * dv, a.y * dv);
}

// --------------------- aggregation 2 + bias/relu + MLP + softmax (fused)
// Round-7 geometry (1 node/wave, low VGPR); phase 1 packed-bf16 dot2
// (proven: 315 us total, r10). Rounds 8/9 proved register-resident
// weights cross the 64-VGPR occupancy cliff and lose.
__global__ __launch_bounds__(256) void k_aggmlp(
    const unsigned* __restrict__ Yu, const int* __restrict__ rowptr,
    const int* __restrict__ col, const float* __restrict__ dinv,
    const float* __restrict__ z, const float* __restrict__ b2,
    const unsigned* __restrict__ W1pk, const float* __restrict__ bp1,
    const float* __restrict__ Wp2T, const float* __restrict__ bp2,
    float* __restrict__ out) {
    __shared__ __align__(16) unsigned h2p[4][64];
    __shared__ __align__(16) float xsh[4][32];
    int t = threadIdx.x, lane = t & 63, w = t >> 6;
    int n = blockIdx.x * 4 + w;
    int s = rowptr[n], e = rowptr[n + 1];
    float2 a = wave_gather<64>(Yu, col, s, e, lane);
    float dv = dinv[n];
    float2 zv = *(const float2*)(z + (size_t)n * 128 + 2 * lane);
    float2 bb = *(const float2*)(b2 + 2 * lane);
    float h2x = fmaxf(zv.x + a.x * dv + bb.x, 0.f);
    float h2y = fmaxf(zv.y + a.y * dv + bb.y, 0.f);
    h2p[w][lane] = packbf(h2x, h2y);   // pair (k=2*lane, 2*lane+1)
    // intra-wave consumers only: lockstep, no barrier

    // phase 1: x = relu(h2 @ Wp1 + bp1) in packed-bf16 dot2 form.
    int j = lane & 31, half = lane >> 5;
    const unsigned* wp = W1pk + (half * 32) * 32 + j;
    float p = 0.f;
    #pragma unroll
    for (int kp = 0; kp < 32; ++kp) {
        unsigned hv = h2p[w][half * 32 + kp];
        unsigned wv = wp[kp * 32];
        asm("v_dot2_f32_bf16 %0, %1, %2, %0" : "+v"(p) : "v"(hv), "v"(wv));
    }
    p += __shfl_xor(p, 32, 64);
    if (half == 0) xsh[w][j] = fmaxf(p + bp1[j], 0.f);

    // phase 2: logits + softmax, all 64 lanes (j8 x kg)
    int j8 = lane >> 3, kg = lane & 7;
    float4 xv = *(const float4*)(&xsh[w][kg * 4]);
    float4 wv2 = *(const float4*)(Wp2T + j8 * 32 + kg * 4);
    float pp = xv.x * wv2.x + xv.y * wv2.y + xv.z * wv2.z + xv.w * wv2.w;
    pp += __shfl_xor(pp, 1, 64);
    pp += __shfl_xor(pp, 2, 64);
    pp += __shfl_xor(pp, 4, 64);
    float lg = pp + bp2[j8];
    float mx = lg;
    mx = fmaxf(mx, __shfl_xor(mx, 8, 64));
    mx = fmaxf(mx, __shfl_xor(mx, 16, 64));
    mx = fmaxf(mx, __shfl_xor(mx, 32, 64));
    float ev = expf(lg - mx);
    float sm = ev;
    sm += __shfl_xor(sm, 8, 64);
    sm += __shfl_xor(sm, 16, 64);
    sm += __shfl_xor(sm, 32, 64);
    if (kg == 0) out[(size_t)n * 8 + j8] = ev / sm;
}

// ------------------------------------------------------- MFMA bf16 GEMM
// v2: double-buffered single-barrier K-loop (r12: +2% vs r10; kept).
// r13 lesson: fusing GEMM1+2 through 113KB LDS halves traffic but drops
// occupancy to 1 block/CU -> net loss. This GEMM is latency-bound and
// needs resident waves more than traffic reduction. Structure frozen.
template<int K, int N, bool EPI1>
__global__ __launch_bounds__(256) void k_gemm_mfma(
    const short* __restrict__ A, const short* __restrict__ BT,
    const float* __restrict__ bias, short* __restrict__ Obf,
    float* __restrict__ Of0) {
    __shared__ short smem[4 * 128 * 32];   // 2 buf x (A 128x32 + B 128x32)
    short* sOut = smem;                    // epilogue reuse: 64 x 128 bf16
    const int t = threadIdx.x;
    const int lane = t & 63;
    const int w = t >> 6;
    const int mBase = blockIdx.x * 128;
    const int nBase = blockIdx.y * 128;
    const int mOff = (w & 1) * 64;
    const int nOff = (w >> 1) * 64;

    floatx4 zero4 = {0.f, 0.f, 0.f, 0.f};
    floatx4 acc[4][4];
    #pragma unroll
    for (int i = 0; i < 4; ++i)
        #pragma unroll
        for (int j = 0; j < 4; ++j) acc[i][j] = zero4;

    const int rL = lane >> 2;
    const int cg = (((lane & 3) ^ ((lane >> 3) & 3))) * 8;
    const int rA = w * 32 + rL;
    const long gA0 = (long)min(mBase + rA,      N_NODES - 1) * K + cg;
    const long gA1 = (long)min(mBase + rA + 16, N_NODES - 1) * K + cg;
    const long gB0 = (long)(nBase + rA)      * K + cg;
    const long gB1 = (long)(nBase + rA + 16) * K + cg;

    const int fr = lane & 15;
    const int csel = (((lane >> 4) ^ ((lane >> 1) & 3))) * 8;

    auto stage = [&](int b, int kt) {
        const int k0 = kt * 32;
        short* sA = smem + b * (2 * 128 * 32);
        short* sB = sA + 128 * 32;
        gld_lds16(A + gA0 + k0, sA + (w * 32) * 32);
        gld_lds16(A + gA1 + k0, sA + (w * 32 + 16) * 32);
        gld_lds16(BT + gB0 + k0, sB + (w * 32) * 32);
        gld_lds16(BT + gB1 + k0, sB + (w * 32 + 16) * 32);
    };

    stage(0, 0);
    int cur = 0;
    for (int kt = 0; kt < K / 32; ++kt) {
        __syncthreads();                       // buf[cur] landed; buf[cur^1] free
        if (kt + 1 < K / 32) stage(cur ^ 1, kt + 1);   // prefetch overlaps compute
        const short* sA = smem + cur * (2 * 128 * 32);
        const short* sB = sA + 128 * 32;
        short8 af[4], bf[4];
        #pragma unroll
        for (int i = 0; i < 4; ++i) {
            af[i] = *(const short8*)(sA + (mOff + i * 16 + fr) * 32 + csel);
            bf[i] = *(const short8*)(sB + (nOff + i * 16 + fr) * 32 + csel);
        }
        #pragma unroll
        for (int mi = 0; mi < 4; ++mi)
            #pragma unroll
            for (int ni = 0; ni < 4; ++ni)
                acc[mi][ni] = __builtin_amdgcn_mfma_f32_16x16x32_bf16(
                    af[mi], bf[ni], acc[mi][ni], 0, 0, 0);
        cur ^= 1;
    }

    // D frag layout: col = lane&15, row = (lane>>4)*4 + reg
    const int cn = lane & 15;
    const int cm = (lane >> 4) * 4;

    if (!EPI1 && nBase < 128) {
        // z output (fp32): direct stores, 16-lane x 4B = 64B contiguous bursts
        #pragma unroll
        for (int ni = 0; ni < 4; ++ni) {
            const int n = nOff + ni * 16 + cn;
            #pragma unroll
            for (int mi = 0; mi < 4; ++mi) {
                #pragma unroll
                for (int r = 0; r < 4; ++r) {
                    const int m = mBase + mOff + mi * 16 + cm + r;
                    if (m < N_NODES) Of0[(size_t)m * 128 + n] = acc[mi][ni][r];
                }
            }
        }
        return;
    }

    // bf16 outputs (h1bf / y1bf): stage 64-row halves in LDS, then store
    // 32 contiguous shorts per thread (4 x b128) -> full-line writes.
    float bv[4];
    #pragma unroll
    for (int ni = 0; ni < 4; ++ni)
        bv[ni] = EPI1 ? bias[nBase + nOff + ni * 16 + cn] : 0.f;
    const int myh = mOff >> 6;
    const int ldc = EPI1 ? N : 128;
    const int cbase = EPI1 ? nBase : 0;
    for (int h = 0; h < 2; ++h) {
        __syncthreads();
        if (myh == h) {
            #pragma unroll
            for (int mi = 0; mi < 4; ++mi)
                #pragma unroll
                for (int ni = 0; ni < 4; ++ni)
                    #pragma unroll
                    for (int r = 0; r < 4; ++r) {
                        int mrow = mi * 16 + cm + r;
                        int nloc = nOff + ni * 16 + cn;
                        float v = acc[mi][ni][r];
                        if (EPI1) v = fmaxf(v + bv[ni], 0.f);
                        sOut[mrow * 128 + nloc] = f2bf(v);
                    }
        }
        __syncthreads();
        int r0 = t >> 2, c0 = (t & 3) * 32;
        int m = mBase + h * 64 + r0;
        if (m < N_NODES) {
            const short* sp = sOut + r0 * 128 + c0;
            short* gp = Obf + (size_t)m * ldc + cbase + c0;
            #pragma unroll
            for (int q = 0; q < 4; ++q)
                *(short8*)(gp + q * 8) = *(const short8*)(sp + q * 8);
        }
    }
}

// ---------------------------------------------------------------- launch
extern "C" void kernel_launch(void* const* d_in, const int* in_sizes, int n_in,
                              void* d_out, int out_size, void* d_ws, size_t ws_size,
                              hipStream_t stream) {
    const float* feat   = (const float*)d_in[0];
    const int*   src    = (const int*)d_in[1];
    const int*   dst    = (const int*)d_in[2];
    const float* W1s    = (const float*)d_in[3];
    const float* W1n    = (const float*)d_in[4];
    const float* b1     = (const float*)d_in[5];
    const float* W2s    = (const float*)d_in[6];
    const float* W2n    = (const float*)d_in[7];
    const float* b2     = (const float*)d_in[8];
    const float* Wp1    = (const float*)d_in[9];
    const float* bp1    = (const float*)d_in[10];
    const float* Wp2    = (const float*)d_in[11];
    const float* bp2    = (const float*)d_in[12];
    float* out = (float*)d_out;

    char* w = (char*)d_ws;
    size_t off = 0;
    auto alloc = [&](size_t bytes) { char* p = w + off; off += (bytes + 255) & ~(size_t)255; return p; };
    int*   deg    = (int*)alloc(N_NODES * 4);
    int*   rowptr = (int*)alloc((N_NODES + 1) * 4);
    int*   cursor = (int*)alloc(N_NODES * 4);
    int*   col    = (int*)alloc((size_t)PADCAP * 4);
    float* dinv   = (float*)alloc(N_NODES * 4);
    int*   bsum   = (int*)alloc(64 * 4);
    int*   boff   = (int*)alloc(64 * 4);
    short* Abf    = (short*)alloc((size_t)(N_NODES + 1) * 256 * 2); // +zero row
    short* W1T    = (short*)alloc((size_t)512 * 256 * 2);
    short* W2T    = (short*)alloc((size_t)256 * 512 * 2);
    short* h1bf   = (short*)alloc((size_t)N_NODES * 512 * 2);
    float* z      = (float*)alloc((size_t)N_NODES * 128 * 4);
    short* y1bf   = (short*)alloc((size_t)(N_NODES + 1) * 128 * 2); // +zero row
    float* Wp2T   = (float*)alloc((size_t)8 * 32 * 4);
    unsigned* W1pk = (unsigned*)alloc((size_t)2048 * 4);

    k_init<<<(PADCAP + 255) / 256, 256, 0, stream>>>(
        deg, col, (int*)(Abf + (size_t)N_NODES * 256),
        (int*)(y1bf + (size_t)N_NODES * 128));
    k_deg<<<N_EDGES / 256, 256, 0, stream>>>(dst, deg);
    k_scan1<<<49, 1024, 0, stream>>>(deg, bsum, dinv);
    k_scan2<<<1, 64, 0, stream>>>(bsum, boff);
    k_scan3<<<49, 1024, 0, stream>>>(deg, boff, rowptr, cursor);
    k_fill<<<NCLS * (N_EDGES / 256), 256, 0, stream>>>(src, dst, cursor, col);
    k_cvt<<<7283, 256, 0, stream>>>(feat, W1s, W1n, W2s, W2n, Wp1, Wp2,
                                    Abf, W1T, W2T, Wp2T, W1pk);
    k_agg<<<N_NODES / 4, 256, 0, stream>>>((const unsigned*)Abf, rowptr, col, dinv, (unsigned*)Abf);
    dim3 g1((N_NODES + 127) / 128, 4);
    k_gemm_mfma<256, 512, true><<<g1, 256, 0, stream>>>(Abf, W1T, b1, h1bf, nullptr);
    dim3 g2((N_NODES + 127) / 128, 2);
    k_gemm_mfma<512, 256, false><<<g2, 256, 0, stream>>>(h1bf, W2T, nullptr, y1bf, z);
    k_aggmlp<<<N_NODES / 4, 256, 0, stream>>>((const unsigned*)y1bf, rowptr, col, dinv, z, b2,
                                              W1pk, bp1, Wp2T, bp2, out);
}

// Round 15
// 304.994 us; speedup vs baseline: 1.0637x; 1.0212x over previous
//
#include <hip/hip_runtime.h>
#include <hip/hip_bf16.h>

#define N_NODES 50000
#define N_EDGES 800000
#define ZROW    N_NODES
#define PADCAP  (N_EDGES + 8 * N_NODES + 64)
#define NCLS    8
#define CLSW    6250   /* nodes per dst-class: 8*6250 = 50000 */

typedef short  short8  __attribute__((ext_vector_type(8)));
typedef float  floatx4 __attribute__((ext_vector_type(4)));

__device__ __forceinline__ short f2bf(float f) {
    union { __hip_bfloat16 h; short s; } u;
    u.h = __float2bfloat16(f);
    return u.s;
}
__device__ __forceinline__ unsigned packbf(float lo, float hi) {
    return ((unsigned)(unsigned short)f2bf(hi) << 16) | (unsigned short)f2bf(lo);
}

// dword (2 packed bf16) dot-accumulate via v_dot2_f32_bf16 inline asm
// (builtin ABI takes short2; (__bf16) value-casts corrupt selectors — r6).
__device__ __forceinline__ void acc2(unsigned v, float& ax, float& ay,
                                     unsigned selLo, unsigned selHi) {
    asm("v_dot2_f32_bf16 %0, %1, %2, %0" : "+v"(ax) : "v"(v), "v"(selLo));
    asm("v_dot2_f32_bf16 %0, %1, %2, %0" : "+v"(ay) : "v"(v), "v"(selHi));
}

__device__ __forceinline__ void gld_lds16(const short* g, short* l) {
    __builtin_amdgcn_global_load_lds(
        (const __attribute__((address_space(1))) int*)g,
        (__attribute__((address_space(3))) int*)l, 16, 0, 0);
}

// ---------------------------------------------------------------- init
__global__ void k_init(int* __restrict__ deg, int* __restrict__ col,
                       int* __restrict__ zrowA, int* __restrict__ zrowY) {
    int i = blockIdx.x * 256 + threadIdx.x;
    if (i < PADCAP) col[i] = ZROW;
    if (i < N_NODES) deg[i] = 0;
    if (i < 128) zrowA[i] = 0;   // Abf zero row: 256 bf16 = 128 ints
    if (i < 64)  zrowY[i] = 0;   // y1bf zero row: 128 bf16 = 64 ints
}

// ---------------------------------------------------------------- CSR build
__global__ void k_deg(const int* __restrict__ dst, int* __restrict__ deg) {
    int e = blockIdx.x * 256 + threadIdx.x;
    if (e < N_EDGES) atomicAdd(&deg[dst[e]], 1);
}

// scans use PADDED degrees (deg+7)&~7: every edge list multiple of 8,
// tail slots stay ZROW -> gather adds exact zeros, no masks needed.
__global__ __launch_bounds__(1024) void k_scan1(const int* __restrict__ deg,
                                                int* __restrict__ bsum,
                                                float* __restrict__ dinv) {
    __shared__ int ws[16];
    int b = blockIdx.x, t = threadIdx.x, i = b * 1024 + t;
    int lane = t & 63, wid = t >> 6;
    int v = (i < N_NODES) ? deg[i] : 0;
    if (i < N_NODES) dinv[i] = 1.0f / fmaxf((float)v, 1.0f);
    int x = (v + 7) & ~7;
    #pragma unroll
    for (int off = 1; off < 64; off <<= 1) x += __shfl_xor(x, off, 64);
    if (lane == 0) ws[wid] = x;
    __syncthreads();
    if (t == 0) {
        int s = 0;
        #pragma unroll
        for (int k = 0; k < 16; ++k) s += ws[k];
        bsum[b] = s;
    }
}

__global__ void k_scan2(const int* __restrict__ bsum, int* __restrict__ boff) {
    int lane = threadIdx.x;
    int v = (lane < 49) ? bsum[lane] : 0;
    int x = v;
    #pragma unroll
    for (int off = 1; off < 64; off <<= 1) {
        int y = __shfl_up(x, off, 64);
        if (lane >= off) x += y;
    }
    if (lane < 49) boff[lane] = x - v;
}

__global__ __launch_bounds__(1024) void k_scan3(const int* __restrict__ deg,
                                                const int* __restrict__ boff,
                                                int* __restrict__ rowptr,
                                                int* __restrict__ cursor) {
    __shared__ int ws[16];
    int b = blockIdx.x, t = threadIdx.x, i = b * 1024 + t;
    int lane = t & 63, wid = t >> 6;
    int v = (i < N_NODES) ? ((deg[i] + 7) & ~7) : 0;
    int x = v;
    #pragma unroll
    for (int off = 1; off < 64; off <<= 1) {
        int y = __shfl_up(x, off, 64);
        if (lane >= off) x += y;
    }
    if (lane == 63) ws[wid] = x;
    __syncthreads();
    if (wid == 0) {
        int s = (lane < 16) ? ws[lane] : 0;
        #pragma unroll
        for (int off = 1; off < 16; off <<= 1) {
            int y = __shfl_up(s, off, 64);
            if (lane >= off) s += y;
        }
        if (lane < 16) ws[lane] = s;
    }
    __syncthreads();
    int waveOff = (wid == 0) ? 0 : ws[wid - 1];
    int incl = x + waveOff + boff[b];
    if (i < N_NODES) { rowptr[i + 1] = incl; cursor[i] = incl - v; }
    if (b == 0 && t == 0) rowptr[0] = 0;
}

// XCD-classed fill (single-owner col slices -> no 16x write amplification)
__global__ __launch_bounds__(256) void k_fill(
    const int* __restrict__ src, const int* __restrict__ dst,
    int* __restrict__ cursor, int* __restrict__ col) {
    int b = blockIdx.x;
    int e = (b >> 3) * 256 + threadIdx.x;
    int lo = (b & 7) * CLSW;
    if (e < N_EDGES) {
        int d = dst[e];
        if ((unsigned)(d - lo) < CLSW) {
            int p = atomicAdd(&cursor[d], 1);
            col[p] = src[e];
        }
    }
}

// ------------------------------------------- fused bf16 conversions
// Builds: Abf (feat bf16), W1T/W2T (bf16 GEMM B), Wp2T (fp32 transposed),
// W1pk (Wp1 packed bf16 pairs for dot2 phase-1).
__global__ void k_cvt(const float* __restrict__ feat,
                      const float* __restrict__ W1s, const float* __restrict__ W1n,
                      const float* __restrict__ W2s, const float* __restrict__ W2n,
                      const float* __restrict__ Wp1, const float* __restrict__ Wp2,
                      short* __restrict__ Abf, short* __restrict__ W1T,
                      short* __restrict__ W2T, float* __restrict__ Wp2T,
                      unsigned* __restrict__ W1pk) {
    int bb = blockIdx.x, t = threadIdx.x;
    if (bb < 6250) {
        int idx = bb * 256 + t;
        if (idx >= N_NODES * 32) return;
        int n = idx >> 5, c = (idx & 31) * 4;
        float4 v = *(const float4*)(feat + (size_t)n * 128 + c);
        *(short4*)(Abf + (size_t)n * 256 + c) =
            make_short4(f2bf(v.x), f2bf(v.y), f2bf(v.z), f2bf(v.w));
    } else {
        int idx = (bb - 6250) * 256 + t;
        if (idx < 512 * 256) {
            int n = idx >> 8, k = idx & 255;
            float v = (k < 128) ? W1s[(size_t)k * 512 + n]
                                : W1n[(size_t)(k - 128) * 512 + n];
            W1T[idx] = f2bf(v);
        } else if (idx < 2 * 512 * 256) {
            int j = idx - 512 * 256;
            int n = j >> 9, k = j & 511;
            float v = (n < 128) ? W2s[(size_t)k * 128 + n]
                                : W2n[(size_t)k * 128 + (n - 128)];
            W2T[j] = f2bf(v);
        } else {
            int r = idx - 2 * 512 * 256;
            if (r < 256) {
                Wp2T[r] = Wp2[(r & 31) * 8 + (r >> 5)];
            } else if (r < 256 + 2048) {
                int q = r - 256;
                int jj = q & 31, kp = (q >> 5) & 31, hh = q >> 10;
                int k0 = hh * 64 + 2 * kp;
                W1pk[q] = packbf(Wp1[(size_t)k0 * 32 + jj],
                                 Wp1[(size_t)(k0 + 1) * 32 + jj]);
            }
        }
    }
}

// -------- wave-per-node gather core: scalar-base (readlane) row loads.
// Padded CSR: (e-s) multiple of 8, col[] always valid -> no masks/branches.
template<int STRIDE>
__device__ __forceinline__ float2 wave_gather(
    const unsigned* __restrict__ U, const int* __restrict__ col,
    int s, int e, int lane) {
    float ax = 0.f, ay = 0.f;
    unsigned selLo = 0x00003F80u;   // bf16 pair (1.0, 0.0)
    unsigned selHi = 0x3F800000u;   // bf16 pair (0.0, 1.0)
    for (int base = s; base < e; base += 64) {
        int cnt = e - base; if (cnt > 64) cnt = 64;   // multiple of 8
        int myc = col[base + lane];                    // padded: always valid
        int j = 0;
        for (; j + 16 <= cnt; j += 16) {
            unsigned v[16];
            #pragma unroll
            for (int u = 0; u < 16; ++u) {
                int c = __builtin_amdgcn_readlane(myc, j + u);
                v[u] = U[(size_t)c * STRIDE + lane];
            }
            #pragma unroll
            for (int u = 0; u < 16; ++u) acc2(v[u], ax, ay, selLo, selHi);
        }
        for (; j < cnt; j += 8) {
            unsigned v[8];
            #pragma unroll
            for (int u = 0; u < 8; ++u) {
                int c = __builtin_amdgcn_readlane(myc, j + u);
                v[u] = U[(size_t)c * STRIDE + lane];
            }
            #pragma unroll
            for (int u = 0; u < 8; ++u) acc2(v[u], ax, ay, selLo, selHi);
        }
    }
    return make_float2(ax, ay);
}

// ---------------------------------------------- aggregation 1 (bf16 gather)
__global__ __launch_bounds__(256) void k_agg(
    const unsigned* __restrict__ Au, const int* __restrict__ rowptr,
    const int* __restrict__ col, const float* __restrict__ dinv,
    unsigned* __restrict__ Aw) {
    int t = threadIdx.x, lane = t & 63, w = t >> 6;
    int n = blockIdx.x * 4 + w;
    int s = rowptr[n], e = rowptr[n + 1];
    float2 a = wave_gather<128>(Au, col, s, e, lane);
    float dv = dinv[n];
    Aw[(size_t)n * 128 + 64 + lane] = packbf(a.x * dv, a.y * dv);
}

// --------------------- aggregation 2 + bias/relu + MLP + softmax (fused)
// Round-7 geometry (1 node/wave, low VGPR); phase 1 packed-bf16 dot2
// (proven: 315 us total, r10). Rounds 8/9 proved register-resident
// weights cross the 64-VGPR occupancy cliff and lose.
__global__ __launch_bounds__(256) void k_aggmlp(
    const unsigned* __restrict__ Yu, const int* __restrict__ rowptr,
    const int* __restrict__ col, const float* __restrict__ dinv,
    const float* __restrict__ z, const float* __restrict__ b2,
    const unsigned* __restrict__ W1pk, const float* __restrict__ bp1,
    const float* __restrict__ Wp2T, const float* __restrict__ bp2,
    float* __restrict__ out) {
    __shared__ __align__(16) unsigned h2p[4][64];
    __shared__ __align__(16) float xsh[4][32];
    int t = threadIdx.x, lane = t & 63, w = t >> 6;
    int n = blockIdx.x * 4 + w;
    int s = rowptr[n], e = rowptr[n + 1];
    float2 a = wave_gather<64>(Yu, col, s, e, lane);
    float dv = dinv[n];
    float2 zv = *(const float2*)(z + (size_t)n * 128 + 2 * lane);
    float2 bb = *(const float2*)(b2 + 2 * lane);
    float h2x = fmaxf(zv.x + a.x * dv + bb.x, 0.f);
    float h2y = fmaxf(zv.y + a.y * dv + bb.y, 0.f);
    h2p[w][lane] = packbf(h2x, h2y);   // pair (k=2*lane, 2*lane+1)
    // intra-wave consumers only: lockstep, no barrier

    // phase 1: x = relu(h2 @ Wp1 + bp1) in packed-bf16 dot2 form.
    int j = lane & 31, half = lane >> 5;
    const unsigned* wp = W1pk + (half * 32) * 32 + j;
    float p = 0.f;
    #pragma unroll
    for (int kp = 0; kp < 32; ++kp) {
        unsigned hv = h2p[w][half * 32 + kp];
        unsigned wv = wp[kp * 32];
        asm("v_dot2_f32_bf16 %0, %1, %2, %0" : "+v"(p) : "v"(hv), "v"(wv));
    }
    p += __shfl_xor(p, 32, 64);
    if (half == 0) xsh[w][j] = fmaxf(p + bp1[j], 0.f);

    // phase 2: logits + softmax, all 64 lanes (j8 x kg)
    int j8 = lane >> 3, kg = lane & 7;
    float4 xv = *(const float4*)(&xsh[w][kg * 4]);
    float4 wv2 = *(const float4*)(Wp2T + j8 * 32 + kg * 4);
    float pp = xv.x * wv2.x + xv.y * wv2.y + xv.z * wv2.z + xv.w * wv2.w;
    pp += __shfl_xor(pp, 1, 64);
    pp += __shfl_xor(pp, 2, 64);
    pp += __shfl_xor(pp, 4, 64);
    float lg = pp + bp2[j8];
    float mx = lg;
    mx = fmaxf(mx, __shfl_xor(mx, 8, 64));
    mx = fmaxf(mx, __shfl_xor(mx, 16, 64));
    mx = fmaxf(mx, __shfl_xor(mx, 32, 64));
    float ev = expf(lg - mx);
    float sm = ev;
    sm += __shfl_xor(sm, 8, 64);
    sm += __shfl_xor(sm, 16, 64);
    sm += __shfl_xor(sm, 32, 64);
    if (kg == 0) out[(size_t)n * 8 + j8] = ev / sm;
}

// ------------------------------------------------------- MFMA bf16 GEMM
// v3: + XCD-aware 1D grid swizzle. r14 PMC: FETCH 51.5MB = 2x A's 25.6MB
// because the NY blocks sharing an A panel (same x, different y) were 391
// apart in dispatch -> different XCDs -> non-coherent L2s re-fetch from
// HBM. Decode bid so same-x blocks share bid%8 (= XCD, round-robin
// heuristic) and are 8 apart in dispatch: panel is L2-hot for readers
// 2..NY. Mechanism is LATENCY (HBM ~900cy -> L2 ~200cy misses) in a
// proven latency-bound kernel (r10-r13: MfmaUtil 11%, dbuf null, fusion
// negative). Mapping is bijective over padded x-range; correctness-free.
template<int K, int N, bool EPI1>
__global__ __launch_bounds__(256) void k_gemm_mfma(
    const short* __restrict__ A, const short* __restrict__ BT,
    const float* __restrict__ bias, short* __restrict__ Obf,
    float* __restrict__ Of0) {
    constexpr int NY  = N / 128;                    // col-chunks sharing A
    constexpr int NXB = (N_NODES + 127) / 128;      // 391
    __shared__ short smem[4 * 128 * 32];   // 2 buf x (A 128x32 + B 128x32)
    short* sOut = smem;                    // epilogue reuse: 64 x 128 bf16
    const int bid = blockIdx.x;
    const int xcd = bid & 7;
    const int q   = bid >> 3;
    const int y   = q % NY;
    const int x   = (q / NY) * 8 + xcd;
    if (x >= NXB) return;
    const int t = threadIdx.x;
    const int lane = t & 63;
    const int w = t >> 6;
    const int mBase = x * 128;
    const int nBase = y * 128;
    const int mOff = (w & 1) * 64;
    const int nOff = (w >> 1) * 64;

    floatx4 zero4 = {0.f, 0.f, 0.f, 0.f};
    floatx4 acc[4][4];
    #pragma unroll
    for (int i = 0; i < 4; ++i)
        #pragma unroll
        for (int j = 0; j < 4; ++j) acc[i][j] = zero4;

    const int rL = lane >> 2;
    const int cg = (((lane & 3) ^ ((lane >> 3) & 3))) * 8;
    const int rA = w * 32 + rL;
    const long gA0 = (long)min(mBase + rA,      N_NODES - 1) * K + cg;
    const long gA1 = (long)min(mBase + rA + 16, N_NODES - 1) * K + cg;
    const long gB0 = (long)(nBase + rA)      * K + cg;
    const long gB1 = (long)(nBase + rA + 16) * K + cg;

    const int fr = lane & 15;
    const int csel = (((lane >> 4) ^ ((lane >> 1) & 3))) * 8;

    auto stage = [&](int b, int kt) {
        const int k0 = kt * 32;
        short* sA = smem + b * (2 * 128 * 32);
        short* sB = sA + 128 * 32;
        gld_lds16(A + gA0 + k0, sA + (w * 32) * 32);
        gld_lds16(A + gA1 + k0, sA + (w * 32 + 16) * 32);
        gld_lds16(BT + gB0 + k0, sB + (w * 32) * 32);
        gld_lds16(BT + gB1 + k0, sB + (w * 32 + 16) * 32);
    };

    stage(0, 0);
    int cur = 0;
    for (int kt = 0; kt < K / 32; ++kt) {
        __syncthreads();                       // buf[cur] landed; buf[cur^1] free
        if (kt + 1 < K / 32) stage(cur ^ 1, kt + 1);   // prefetch overlaps compute
        const short* sA = smem + cur * (2 * 128 * 32);
        const short* sB = sA + 128 * 32;
        short8 af[4], bf[4];
        #pragma unroll
        for (int i = 0; i < 4; ++i) {
            af[i] = *(const short8*)(sA + (mOff + i * 16 + fr) * 32 + csel);
            bf[i] = *(const short8*)(sB + (nOff + i * 16 + fr) * 32 + csel);
        }
        #pragma unroll
        for (int mi = 0; mi < 4; ++mi)
            #pragma unroll
            for (int ni = 0; ni < 4; ++ni)
                acc[mi][ni] = __builtin_amdgcn_mfma_f32_16x16x32_bf16(
                    af[mi], bf[ni], acc[mi][ni], 0, 0, 0);
        cur ^= 1;
    }

    // D frag layout: col = lane&15, row = (lane>>4)*4 + reg
    const int cn = lane & 15;
    const int cm = (lane >> 4) * 4;

    if (!EPI1 && nBase < 128) {
        // z output (fp32): direct stores, 16-lane x 4B = 64B contiguous bursts
        #pragma unroll
        for (int ni = 0; ni < 4; ++ni) {
            const int n = nOff + ni * 16 + cn;
            #pragma unroll
            for (int mi = 0; mi < 4; ++mi) {
                #pragma unroll
                for (int r = 0; r < 4; ++r) {
                    const int m = mBase + mOff + mi * 16 + cm + r;
                    if (m < N_NODES) Of0[(size_t)m * 128 + n] = acc[mi][ni][r];
                }
            }
        }
        return;
    }

    // bf16 outputs (h1bf / y1bf): stage 64-row halves in LDS, then store
    // 32 contiguous shorts per thread (4 x b128) -> full-line writes.
    float bv[4];
    #pragma unroll
    for (int ni = 0; ni < 4; ++ni)
        bv[ni] = EPI1 ? bias[nBase + nOff + ni * 16 + cn] : 0.f;
    const int myh = mOff >> 6;
    const int ldc = EPI1 ? N : 128;
    const int cbase = EPI1 ? nBase : 0;
    for (int h = 0; h < 2; ++h) {
        __syncthreads();
        if (myh == h) {
            #pragma unroll
            for (int mi = 0; mi < 4; ++mi)
                #pragma unroll
                for (int ni = 0; ni < 4; ++ni)
                    #pragma unroll
                    for (int r = 0; r < 4; ++r) {
                        int mrow = mi * 16 + cm + r;
                        int nloc = nOff + ni * 16 + cn;
                        float v = acc[mi][ni][r];
                        if (EPI1) v = fmaxf(v + bv[ni], 0.f);
                        sOut[mrow * 128 + nloc] = f2bf(v);
                    }
        }
        __syncthreads();
        int r0 = t >> 2, c0 = (t & 3) * 32;
        int m = mBase + h * 64 + r0;
        if (m < N_NODES) {
            const short* sp = sOut + r0 * 128 + c0;
            short* gp = Obf + (size_t)m * ldc + cbase + c0;
            #pragma unroll
            for (int qq = 0; qq < 4; ++qq)
                *(short8*)(gp + qq * 8) = *(const short8*)(sp + qq * 8);
        }
    }
}

// ---------------------------------------------------------------- launch
extern "C" void kernel_launch(void* const* d_in, const int* in_sizes, int n_in,
                              void* d_out, int out_size, void* d_ws, size_t ws_size,
                              hipStream_t stream) {
    const float* feat   = (const float*)d_in[0];
    const int*   src    = (const int*)d_in[1];
    const int*   dst    = (const int*)d_in[2];
    const float* W1s    = (const float*)d_in[3];
    const float* W1n    = (const float*)d_in[4];
    const float* b1     = (const float*)d_in[5];
    const float* W2s    = (const float*)d_in[6];
    const float* W2n    = (const float*)d_in[7];
    const float* b2     = (const float*)d_in[8];
    const float* Wp1    = (const float*)d_in[9];
    const float* bp1    = (const float*)d_in[10];
    const float* Wp2    = (const float*)d_in[11];
    const float* bp2    = (const float*)d_in[12];
    float* out = (float*)d_out;

    char* w = (char*)d_ws;
    size_t off = 0;
    auto alloc = [&](size_t bytes) { char* p = w + off; off += (bytes + 255) & ~(size_t)255; return p; };
    int*   deg    = (int*)alloc(N_NODES * 4);
    int*   rowptr = (int*)alloc((N_NODES + 1) * 4);
    int*   cursor = (int*)alloc(N_NODES * 4);
    int*   col    = (int*)alloc((size_t)PADCAP * 4);
    float* dinv   = (float*)alloc(N_NODES * 4);
    int*   bsum   = (int*)alloc(64 * 4);
    int*   boff   = (int*)alloc(64 * 4);
    short* Abf    = (short*)alloc((size_t)(N_NODES + 1) * 256 * 2); // +zero row
    short* W1T    = (short*)alloc((size_t)512 * 256 * 2);
    short* W2T    = (short*)alloc((size_t)256 * 512 * 2);
    short* h1bf   = (short*)alloc((size_t)N_NODES * 512 * 2);
    float* z      = (float*)alloc((size_t)N_NODES * 128 * 4);
    short* y1bf   = (short*)alloc((size_t)(N_NODES + 1) * 128 * 2); // +zero row
    float* Wp2T   = (float*)alloc((size_t)8 * 32 * 4);
    unsigned* W1pk = (unsigned*)alloc((size_t)2048 * 4);

    k_init<<<(PADCAP + 255) / 256, 256, 0, stream>>>(
        deg, col, (int*)(Abf + (size_t)N_NODES * 256),
        (int*)(y1bf + (size_t)N_NODES * 128));
    k_deg<<<N_EDGES / 256, 256, 0, stream>>>(dst, deg);
    k_scan1<<<49, 1024, 0, stream>>>(deg, bsum, dinv);
    k_scan2<<<1, 64, 0, stream>>>(bsum, boff);
    k_scan3<<<49, 1024, 0, stream>>>(deg, boff, rowptr, cursor);
    k_fill<<<NCLS * (N_EDGES / 256), 256, 0, stream>>>(src, dst, cursor, col);
    k_cvt<<<7283, 256, 0, stream>>>(feat, W1s, W1n, W2s, W2n, Wp1, Wp2,
                                    Abf, W1T, W2T, Wp2T, W1pk);
    k_agg<<<N_NODES / 4, 256, 0, stream>>>((const unsigned*)Abf, rowptr, col, dinv, (unsigned*)Abf);
    k_gemm_mfma<256, 512, true><<<392 * 4, 256, 0, stream>>>(Abf, W1T, b1, h1bf, nullptr);
    k_gemm_mfma<512, 256, false><<<392 * 2, 256, 0, stream>>>(h1bf, W2T, nullptr, y1bf, z);
    k_aggmlp<<<N_NODES / 4, 256, 0, stream>>>((const unsigned*)y1bf, rowptr, col, dinv, z, b2,
                                              W1pk, bp1, Wp2T, bp2, out);
}